// Round 1
// baseline (2980.959 us; speedup 1.0000x reference)
//
#include <hip/hip_runtime.h>
#include <cstdint>
#include <cstddef>

#define DEV __device__ __forceinline__

typedef __attribute__((ext_vector_type(4))) float f32x4;
typedef __attribute__((ext_vector_type(8))) short s16x8;

// ---------------- bf16 split helpers (RNE) ----------------
DEV uint16_t f2bf(float x){
  union { float f; uint32_t u; } v; v.f = x;
  uint32_t r = v.u + 0x7FFFu + ((v.u >> 16) & 1u);
  return (uint16_t)(r >> 16);
}
DEV float bf2f(uint16_t h){
  union { uint32_t u; float f; } v; v.u = ((uint32_t)h) << 16; return v.f;
}
DEV void split2(float x, uint16_t &hi, uint16_t &lo){
  hi = f2bf(x); lo = f2bf(x - bf2f(hi));
}

DEV f32x4 mfma16(s16x8 a, s16x8 b, f32x4 c){
  return __builtin_amdgcn_mfma_f32_16x16x32_bf16(a, b, c, 0, 0, 0);
}

// async 16B global->LDS (per-lane global addr; LDS side is wave base + lane*16)
DEV void g2l16(const void* g, void* l){
  __builtin_amdgcn_global_load_lds(
      (const __attribute__((address_space(1))) unsigned int*)g,
      (__attribute__((address_space(3))) unsigned int*)l, 16, 0, 0);
}

// ---------------- small utility kernels ----------------
__global__ __launch_bounds__(256) void zero_f32(float* __restrict__ p, int n){
  int i = blockIdx.x * 256 + threadIdx.x;
  if (i < n) p[i] = 0.f;
}

// e = emb[x]  -> split bf16 hi/lo, [4096][512]
__global__ __launch_bounds__(256) void gather_split(
    const int* __restrict__ x, const float* __restrict__ emb,
    uint16_t* __restrict__ ehi, uint16_t* __restrict__ elo){
  int idx = blockIdx.x * 256 + threadIdx.x;      // float4 units: 4096*128
  int r = idx >> 7, k4 = idx & 127;
  int row = x[r];
  float4 v = ((const float4*)(emb + (size_t)row * 512))[k4];
  ushort4 hi, lo;
  split2(v.x, hi.x, lo.x);
  split2(v.y, hi.y, lo.y);
  split2(v.z, hi.z, lo.z);
  split2(v.w, hi.w, lo.w);
  ((ushort4*)ehi)[idx] = hi;
  ((ushort4*)elo)[idx] = lo;
}

// in[R][C] fp32 -> out_hi/out_lo [C][R] bf16 (transpose + split)
__global__ __launch_bounds__(256) void transpose_split(
    const float* __restrict__ in, uint16_t* __restrict__ ohi,
    uint16_t* __restrict__ olo, int R, int Cc){
  __shared__ float tile[32][33];
  const int tx = threadIdx.x & 31, ty = threadIdx.x >> 5;  // 32 x 8
  const int c0 = blockIdx.x << 5, r0 = blockIdx.y << 5;
  for (int i = 0; i < 32; i += 8)
    tile[ty + i][tx] = in[(size_t)(r0 + ty + i) * Cc + c0 + tx];
  __syncthreads();
  for (int i = 0; i < 32; i += 8){
    float v = tile[tx][ty + i];
    uint16_t hi, lo; split2(v, hi, lo);
    size_t o = (size_t)(c0 + ty + i) * R + r0 + tx;
    ohi[o] = hi; olo[o] = lo;
  }
}

// rec_kernel fp32 [1024][4096] -> packed MFMA B-fragment layout
// [ntile(256)][kb(32)][lane(64)][8] bf16, element = Wr[kb*32+(lane>>4)*8+j][ntile*16+(lane&15)]
__global__ __launch_bounds__(256) void pack_wr(
    const float* __restrict__ wr, uint16_t* __restrict__ phi, uint16_t* __restrict__ plo){
  int t = blockIdx.x * 256 + threadIdx.x;        // 0..524287
  int lane = t & 63, kb = (t >> 6) & 31, ntile = t >> 11;
  int q = lane >> 4, ln = lane & 15;
  int n = (ntile << 4) + ln;
  int k0 = (kb << 5) + (q << 3);
  union { s16x8 v; uint16_t e[8]; } uh, ul;
  for (int j = 0; j < 8; j++)
    split2(wr[(size_t)(k0 + j) * 4096 + n], uh.e[j], ul.e[j]);
  ((s16x8*)phi)[t] = uh.v;
  ((s16x8*)plo)[t] = ul.v;
}

// ---------------- split-bf16 GEMM ----------------
// C[M][N] fp32 = A[M][K] * B^T[N][K] + bias[N], A/B as bf16 hi/lo pairs.
// 128x128 tile, BK=32, 256 threads (4 waves, each 64x64), global_load_lds staging,
// XOR swizzle p(row)=(row+(row>>2))&3 on the 4 16B-chunks of each 32-elem row.
__global__ __launch_bounds__(256) void gemm_split(
    const uint16_t* __restrict__ Ahi, const uint16_t* __restrict__ Alo,
    const uint16_t* __restrict__ Bhi, const uint16_t* __restrict__ Blo,
    const float* __restrict__ bias, float* __restrict__ C,
    int Mm, int Nn, int Kk){
  __shared__ __attribute__((aligned(16))) uint16_t sAhi[128 * 32];
  __shared__ __attribute__((aligned(16))) uint16_t sAlo[128 * 32];
  __shared__ __attribute__((aligned(16))) uint16_t sBhi[128 * 32];
  __shared__ __attribute__((aligned(16))) uint16_t sBlo[128 * 32];

  const int tid = threadIdx.x;
  const int lane = tid & 63, wid = tid >> 6;
  const int wm = (wid & 1) * 64, wn = (wid >> 1) * 64;
  const int q = lane >> 4, lm = lane & 15;

  // block swizzle: groups of GROUP n-tiles share B panels in L2
  const int gm = Mm >> 7, gn = Nn >> 7;
  const int GROUP = 10;
  const int per = gm * GROUP;
  const int gi = blockIdx.x / per;
  const int rem = blockIdx.x - gi * per;
  const int n0g = gi * GROUP;
  int gw = gn - n0g; if (gw > GROUP) gw = GROUP;
  const int mt = rem / gw;
  const int nt = n0g + rem % gw;
  const int m0 = mt << 7, n0 = nt << 7;

  // staging addresses: LDS slot s = tid (+256 pass2); row = s>>2, chunk-slot = s&3,
  // holds global chunk c = (s&3) ^ p(row)
  const int row0 = tid >> 2;
  const int csw  = (tid & 3) ^ ((row0 + (row0 >> 2)) & 3);   // p(row+64)==p(row)
  const size_t aoff0 = (size_t)(m0 + row0) * Kk + csw * 8;
  const size_t aoff1 = (size_t)(m0 + row0 + 64) * Kk + csw * 8;
  const size_t boff0 = (size_t)(n0 + row0) * Kk + csw * 8;
  const size_t boff1 = (size_t)(n0 + row0 + 64) * Kk + csw * 8;
  uint16_t* ldsA0h = sAhi + tid * 8; uint16_t* ldsA1h = sAhi + 2048 + tid * 8;
  uint16_t* ldsA0l = sAlo + tid * 8; uint16_t* ldsA1l = sAlo + 2048 + tid * 8;
  uint16_t* ldsB0h = sBhi + tid * 8; uint16_t* ldsB1h = sBhi + 2048 + tid * 8;
  uint16_t* ldsB0l = sBlo + tid * 8; uint16_t* ldsB1l = sBlo + 2048 + tid * 8;

  const int qs8 = ((q ^ ((lm + (lm >> 2)) & 3)) * 8);  // swizzled chunk offset (halfwords)

  f32x4 acc[4][4];
  for (int i = 0; i < 4; i++) for (int j = 0; j < 4; j++)
    acc[i][j] = (f32x4){0.f, 0.f, 0.f, 0.f};

  for (int ks = 0; ks < Kk; ks += 32){
    __syncthreads();
    g2l16(Ahi + aoff0 + ks, ldsA0h);
    g2l16(Ahi + aoff1 + ks, ldsA1h);
    g2l16(Alo + aoff0 + ks, ldsA0l);
    g2l16(Alo + aoff1 + ks, ldsA1l);
    g2l16(Bhi + boff0 + ks, ldsB0h);
    g2l16(Bhi + boff1 + ks, ldsB1h);
    g2l16(Blo + boff0 + ks, ldsB0l);
    g2l16(Blo + boff1 + ks, ldsB1l);
    __syncthreads();

    s16x8 bh[4], bl[4];
    for (int j = 0; j < 4; j++){
      bh[j] = *(const s16x8*)&sBhi[(wn + j * 16 + lm) * 32 + qs8];
      bl[j] = *(const s16x8*)&sBlo[(wn + j * 16 + lm) * 32 + qs8];
    }
    for (int i = 0; i < 4; i++){
      s16x8 ah = *(const s16x8*)&sAhi[(wm + i * 16 + lm) * 32 + qs8];
      s16x8 al = *(const s16x8*)&sAlo[(wm + i * 16 + lm) * 32 + qs8];
      for (int j = 0; j < 4; j++){
        acc[i][j] = mfma16(ah, bh[j], acc[i][j]);
        acc[i][j] = mfma16(ah, bl[j], acc[i][j]);
        acc[i][j] = mfma16(al, bh[j], acc[i][j]);
      }
    }
  }

  for (int i = 0; i < 4; i++){
    const int rowg = m0 + wm + i * 16 + q * 4;
    for (int j = 0; j < 4; j++){
      const int colg = n0 + wn + j * 16 + lm;
      const float bv = bias[colg];
      for (int r = 0; r < 4; r++)
        C[(size_t)(rowg + r) * Nn + colg] = acc[i][j][r] + bv;
    }
  }
}

// ---------------- LSTM step ----------------
// 64 blocks x 256 threads. Block owns h-cols [blk*16, blk*16+16); wave g computes gate g.
__global__ __launch_bounds__(256) void lstm_step(
    const uint16_t* __restrict__ hin_hi, const uint16_t* __restrict__ hin_lo,
    const uint16_t* __restrict__ wphi, const uint16_t* __restrict__ wplo,
    const float* __restrict__ zx, float* __restrict__ c,
    uint16_t* __restrict__ hout_hi, uint16_t* __restrict__ hout_lo,
    uint16_t* __restrict__ hseq_hi, uint16_t* __restrict__ hseq_lo, int t){
  __shared__ __attribute__((aligned(16))) uint16_t sh[16 * 1024];
  __shared__ __attribute__((aligned(16))) uint16_t sl[16 * 1024];

  const int tid = threadIdx.x, lane = tid & 63, g = tid >> 6;
  const int q = lane >> 4, lm = lane & 15;
  const int blk = blockIdx.x;

  // stage h (hi+lo) into LDS, chunk-swizzled: row b, chunk ch stored at ch^(b&7)
  for (int ii = 0; ii < 8; ii++){
    int cid = ii * 256 + tid;                 // 0..2047 (b = cid>>7, kc = cid&127)
    int b = cid >> 7, kc = cid & 127;
    int dst = b * 1024 + ((kc ^ (b & 7)) << 3);
    *(s16x8*)&sh[dst] = *(const s16x8*)&hin_hi[cid * 8];
    *(s16x8*)&sl[dst] = *(const s16x8*)&hin_lo[cid * 8];
  }
  __syncthreads();

  f32x4 acc = (f32x4){0.f, 0.f, 0.f, 0.f};
  const int xm = lm & 7;
  const int qlow = ((q ^ (xm & 3)) << 3);     // halfwords
  const int axor = ((xm & 4) << 3);           // chunk bit2 flip, halfwords
  const int ntile = g * 64 + blk;
  const uint16_t* bph = wphi + ((size_t)ntile * 2048 + lane) * 8;
  const uint16_t* bpl = wplo + ((size_t)ntile * 2048 + lane) * 8;

  for (int kb = 0; kb < 32; kb++){
    const int aoff = lm * 1024 + (((kb << 5) ^ axor) + qlow);
    s16x8 ah = *(const s16x8*)&sh[aoff];
    s16x8 al = *(const s16x8*)&sl[aoff];
    s16x8 bh = *(const s16x8*)&bph[kb * 512];
    s16x8 bl = *(const s16x8*)&bpl[kb * 512];
    acc = mfma16(ah, bh, acc);
    acc = mfma16(ah, bl, acc);
    acc = mfma16(al, bh, acc);
  }
  __syncthreads();

  float* zbuf = (float*)sh;                   // [4][16][17], overlays sh (done reading)
  for (int r = 0; r < 4; r++)
    zbuf[(g * 16 + q * 4 + r) * 17 + lm] = acc[r];
  __syncthreads();

  const int b = tid >> 4, j = tid & 15;
  const int col = blk * 16 + j;
  const size_t r = (size_t)b * 256 + t;
  const float* zr = zx + r * 4096 + col;
  float zi = zbuf[(0 * 16 + b) * 17 + j] + zr[0];
  float zf = zbuf[(1 * 16 + b) * 17 + j] + zr[1024];
  float zg = zbuf[(2 * 16 + b) * 17 + j] + zr[2048];
  float zo = zbuf[(3 * 16 + b) * 17 + j] + zr[3072];
  float ig = 1.f / (1.f + __expf(-zi));
  float fg = 1.f / (1.f + __expf(-zf));
  float gg = 1.f - 2.f / (__expf(2.f * zg) + 1.f);
  float og = 1.f / (1.f + __expf(-zo));
  float cn = fg * c[b * 1024 + col] + ig * gg;
  c[b * 1024 + col] = cn;
  float h = og * (1.f - 2.f / (__expf(2.f * cn) + 1.f));
  uint16_t hh, hl; split2(h, hh, hl);
  hout_hi[b * 1024 + col] = hh;
  hout_lo[b * 1024 + col] = hl;
  hseq_hi[r * 1024 + col] = hh;
  hseq_lo[r * 1024 + col] = hl;
}

// ---------------- launch ----------------
extern "C" void kernel_launch(void* const* d_in, const int* in_sizes, int n_in,
                              void* d_out, int out_size, void* d_ws, size_t ws_size,
                              hipStream_t stream){
  (void)in_sizes; (void)n_in; (void)out_size; (void)ws_size;
  const int*   x    = (const int*)d_in[0];
  const float* emb  = (const float*)d_in[1];
  const float* wk   = (const float*)d_in[2];   // [512][4096]
  const float* wr   = (const float*)d_in[3];   // [1024][4096]
  const float* bias = (const float*)d_in[4];   // [4096]
  const float* wo   = (const float*)d_in[5];   // [1024][32000]
  const float* bo   = (const float*)d_in[6];   // [32000]
  float* out = (float*)d_out;                  // [4096][32000]

  char* w = (char*)d_ws;
  float*    zx    = (float*)w;    w += (size_t)4096 * 4096 * 4;   // 64 MB
  uint16_t* ehi   = (uint16_t*)w; w += (size_t)4096 * 512 * 2;
  uint16_t* elo   = (uint16_t*)w; w += (size_t)4096 * 512 * 2;
  uint16_t* kthi  = (uint16_t*)w; w += (size_t)4096 * 512 * 2;    // kernel^T [4096][512]
  uint16_t* ktlo  = (uint16_t*)w; w += (size_t)4096 * 512 * 2;
  uint16_t* wphi  = (uint16_t*)w; w += (size_t)1024 * 4096 * 2;   // packed rec_kernel
  uint16_t* wplo  = (uint16_t*)w; w += (size_t)1024 * 4096 * 2;
  uint16_t* wothi = (uint16_t*)w; w += (size_t)32000 * 1024 * 2;  // w_out^T [32000][1024]
  uint16_t* wotlo = (uint16_t*)w; w += (size_t)32000 * 1024 * 2;
  uint16_t* hshi  = (uint16_t*)w; w += (size_t)4096 * 1024 * 2;   // h_seq [4096][1024]
  uint16_t* hslo  = (uint16_t*)w; w += (size_t)4096 * 1024 * 2;
  float*    c     = (float*)w;    w += (size_t)16 * 1024 * 4;     // cell state
  uint16_t* h0hi  = (uint16_t*)w; w += (size_t)16 * 1024 * 2;     // h ping-pong
  uint16_t* h0lo  = (uint16_t*)w; w += (size_t)16 * 1024 * 2;
  uint16_t* h1hi  = (uint16_t*)w; w += (size_t)16 * 1024 * 2;
  uint16_t* h1lo  = (uint16_t*)w; w += (size_t)16 * 1024 * 2;

  // zero c + all four h buffers (contiguous: 65536 + 4*32768 bytes = 49152 floats)
  zero_f32<<<192, 256, 0, stream>>>(c, 49152);
  gather_split<<<2048, 256, 0, stream>>>(x, emb, ehi, elo);
  transpose_split<<<dim3(128, 16), 256, 0, stream>>>(wk, kthi, ktlo, 512, 4096);
  pack_wr<<<2048, 256, 0, stream>>>(wr, wphi, wplo);
  transpose_split<<<dim3(1000, 32), 256, 0, stream>>>(wo, wothi, wotlo, 1024, 32000);

  // zx = e @ kernel + bias   [4096][4096]
  gemm_split<<<1024, 256, 0, stream>>>(ehi, elo, kthi, ktlo, bias, zx, 4096, 4096, 512);

  for (int t = 0; t < 256; t++){
    const uint16_t* ihi = (t & 1) ? h1hi : h0hi;
    const uint16_t* ilo = (t & 1) ? h1lo : h0lo;
    uint16_t* ohi = (t & 1) ? h0hi : h1hi;
    uint16_t* olo = (t & 1) ? h0lo : h1lo;
    lstm_step<<<64, 256, 0, stream>>>(ihi, ilo, wphi, wplo, zx, c,
                                      ohi, olo, hshi, hslo, t);
  }

  // logits = h_seq @ w_out + b_out   [4096][32000]
  gemm_split<<<8000, 256, 0, stream>>>(hshi, hslo, wothi, wotlo, bo, out,
                                       4096, 32000, 1024);
}